// Round 5
// baseline (851.464 us; speedup 1.0000x reference)
//
#include <hip/hip_runtime.h>
#include <hip/hip_bf16.h>
#include <math.h>

#define BB 64
#define TT 1024
#define KK 128
#define START_TAG 126
#define NB 16              // batches per block -> 4 blocks
#define CS 8               // steps per F chunk (double-buffered)
#define NCH (TT / CS)      // 128 chunks
#define FSTR 34            // per-lane F slot stride in floats (136 B: 2-way banks, 8B-aligned)

typedef short bf16x8 __attribute__((ext_vector_type(8)));
typedef float f32x4 __attribute__((ext_vector_type(4)));

__device__ __forceinline__ short f2bf(float f) {
  union { __hip_bfloat16 h; short s; } u;
  u.h = __float2bfloat16(f);
  return u.s;
}

// Step: C(128x16) = E(128x128) . U(128x16) via 32 mfma_f32_16x16x32_bf16 on ONE wave.
//  A-frag (m89/m120 verified): lane holds A[m=lane&15][k=(lane>>4)*8+j]
//  B-frag:                     lane holds B[k=(lane>>4)*8+j][n=lane&15]
//  C-frag:                     lane holds C[row=16*mi+4*(lane>>4)+reg][col=lane&15]
// U LDS layout [k>>3][n][k&7] (bf16): B-read = 4x ds_read_b128 (2-way banks, free);
// C-write = 8x ds_write_b64. Wave-ordered DS => no barrier inside the step loop.
// Deferred normalization (R4-validated): u(t) = C .* F(t) * rcp(sigma_prev);
// sigma(t) = C[126][n] = sum_k U(t-1)[k][n] (E row START is all-ones);
// fwd_n = M0_n + ln2 * sum log2(sigma) with gating for per-batch lens.
__global__ __launch_bounds__(256, 1) void crf_forward_mfma(
    const float* __restrict__ feats,   // [B,T,K]
    const int*   __restrict__ tags,    // [B,T]
    const int*   __restrict__ lens,    // [B]
    const float* __restrict__ trans,   // [K,K]
    float*       __restrict__ fwd_pb,  // [B]
    float*       __restrict__ gold_pb) // [B]
{
  __shared__ __align__(16) float Fbuf[2][CS * 64 * FSTR];  // 2 x 69632 B
  __shared__ __align__(16) short Ubuf[2048];               // U: 128k x 16n bf16
  __shared__ __align__(16) float maxT_s[KK];

  const int tid  = threadIdx.x;
  const int wv   = tid >> 6;
  const int lane = tid & 63;
  const int bb0  = blockIdx.x * NB;

  // ---- stage T into Fbuf[1] (16384 <= 17408 floats); zero U ----
  float* Tst = &Fbuf[1][0];
  for (int i = tid; i < KK * KK; i += 256) Tst[i] = trans[i];
  for (int i = tid; i < 2048; i += 256) Ubuf[i] = 0;
  __syncthreads();
  if (tid < KK) {
    float m = -INFINITY;
    for (int k = 0; k < KK; ++k) m = fmaxf(m, Tst[tid * KK + k]);
    maxT_s[tid] = m;
  }
  // U(0) = onehot(START=126) for every batch column: element (126>>3)*128 + n*8 + (126&7)
  if (tid < NB) Ubuf[15 * 128 + tid * 8 + 6] = (short)0x3F80;  // bf16 1.0
  __syncthreads();

  if (wv == 0) {
    // =========================== MFMA chain wave ===========================
    const int m_ = lane & 15, qq = lane >> 4;
    bf16x8 Er[8][4];
    for (int mi = 0; mi < 8; ++mi)
      for (int ki = 0; ki < 4; ++ki) {
        const int row = 16 * mi + m_;
        const float mT = maxT_s[row];
        bf16x8 e;
        for (int j = 0; j < 8; ++j)
          e[j] = f2bf(__expf(Tst[row * KK + 32 * ki + 8 * qq + j] - mT));
        Er[mi][ki] = e;
      }
    const int Ln = lens[bb0 + m_];       // this lane's batch (col n = m_)
    float sigma_prev = 1.0f;
    float Macc2 = 0.0f;
    const int wBase = (qq >> 1) * 128 + m_ * 8 + 4 * (qq & 1);
    __syncthreads();                     // chunk-0 F ready

    for (int c = 0; c < NCH; ++c) {
      const float* Fc = Fbuf[c & 1];
      for (int tc = (c == 0) ? 1 : 0; tc < CS; ++tc) {
        const int t = c * CS + tc;
        const float rr = __builtin_amdgcn_rcpf(sigma_prev);
        const float2* f2p = (const float2*)&Fc[(tc * 64 + lane) * FSTR];
        float2 Fv[16];
        #pragma unroll
        for (int i = 0; i < 16; ++i) Fv[i] = f2p[i];
        bf16x8 Bk[4];
        #pragma unroll
        for (int ki = 0; ki < 4; ++ki)
          Bk[ki] = *(const bf16x8*)&Ubuf[(4 * ki + qq) * 128 + m_ * 8];
        f32x4 acc[8];
        #pragma unroll
        for (int mi = 0; mi < 8; ++mi) {
          f32x4 a = {0.f, 0.f, 0.f, 0.f};
          #pragma unroll
          for (int ki = 0; ki < 4; ++ki)
            a = __builtin_amdgcn_mfma_f32_16x16x32_bf16(Er[mi][ki], Bk[ki], a, 0, 0, 0);
          acc[mi] = a;
        }
        // sigma(t) = C[126][n]: mi=7, qq=3, reg=2 -> lanes 48..63
        const float sg = __shfl(acc[7][2], 48 + m_, 64);
        const bool gate = (t <= Ln - 2) || (t == Ln);
        Macc2 += gate ? __log2f(sg) : 0.0f;
        // scale, cvt to bf16, store u(t)
        #pragma unroll
        for (int mi = 0; mi < 8; ++mi) {
          const float x0 = acc[mi][0] * Fv[2 * mi].x * rr;
          const float x1 = acc[mi][1] * Fv[2 * mi].y * rr;
          const float x2 = acc[mi][2] * Fv[2 * mi + 1].x * rr;
          const float x3 = acc[mi][3] * Fv[2 * mi + 1].y * rr;
          union { __hip_bfloat162 h; unsigned u; } lo, hi;
          lo.h = __float22bfloat162_rn(make_float2(x0, x1));
          hi.h = __float22bfloat162_rn(make_float2(x2, x3));
          uint2 wr; wr.x = lo.u; wr.y = hi.u;
          *(uint2*)&Ubuf[wBase + 256 * mi] = wr;
        }
        sigma_prev = sg;
      }
      __syncthreads();
    }
    // final pass: sigma(T) = sum_k u(T-1) via tile-7 only (for batches with L == T)
    bf16x8 BkF[4];
    #pragma unroll
    for (int ki = 0; ki < 4; ++ki)
      BkF[ki] = *(const bf16x8*)&Ubuf[(4 * ki + qq) * 128 + m_ * 8];
    f32x4 a7 = {0.f, 0.f, 0.f, 0.f};
    #pragma unroll
    for (int ki = 0; ki < 4; ++ki)
      a7 = __builtin_amdgcn_mfma_f32_16x16x32_bf16(Er[7][ki], BkF[ki], a7, 0, 0, 0);
    const float sgT = __shfl(a7[2], 48 + m_, 64);
    if (Ln == TT) Macc2 += __log2f(sgT);
    if (qq == 0) {
      const float M0 = feats[(size_t)(bb0 + m_) * TT * KK + START_TAG];
      fwd_pb[bb0 + m_] = M0 + 0.69314718055994531f * Macc2;
    }
  } else if (wv < 3) {
    // =========================== F producers (waves 1,2) ===========================
    const int p = (wv - 1) * 64 + lane;  // 0..127
    const int a = p & 31;                // fixed 4-row group per lane
    const float4 mT4 = *(const float4*)&maxT_s[4 * a];
    auto fill = [&](int cc) {
      float* dstF = &Fbuf[cc & 1][0];
      #pragma unroll 4
      for (int k = 0; k < 32; ++k) {
        const int u  = p + 128 * k;
        const int tc = u >> 9;
        const int n  = (u >> 5) & 15;
        const int t  = cc * CS + tc;
        const float4 v = *(const float4*)(feats + ((size_t)(bb0 + n) * TT + t) * KK + 4 * a);
        float2 e0, e1;
        e0.x = __expf(v.x + mT4.x); e0.y = __expf(v.y + mT4.y);
        e1.x = __expf(v.z + mT4.z); e1.y = __expf(v.w + mT4.w);
        // target: wave-0 lane (n + 16*(a&3)), slots (a>>2)*4 .. +3  (C-layout)
        float* dp = &dstF[(tc * 64 + (n + 16 * (a & 3))) * FSTR + (a >> 2) * 4];
        ((float2*)dp)[0] = e0;
        ((float2*)dp)[1] = e1;
      }
    };
    fill(0);
    __syncthreads();                     // chunk-0 F ready
    for (int c = 0; c < NCH; ++c) {
      if (c + 1 < NCH) fill(c + 1);
      __syncthreads();
    }
  } else {
    // =========================== gold score (wave 3) ===========================
    const int n = lane & 15, part = lane >> 4;
    const int bI = bb0 + n;
    const int Lb = lens[bI];
    const float* fb = feats + (size_t)bI * TT * KK;
    const int* tg = tags + bI * TT;
    float g = 0.f;
    for (int t = part; t < TT; t += 4) {
      if (t < Lb) {
        const int tag = tg[t];
        g += fb[(size_t)t * KK + tag];
        if (t < Lb - 1) g += trans[tg[t + 1] * KK + tag];
      }
    }
    g += __shfl_xor(g, 16, 64);
    g += __shfl_xor(g, 32, 64);
    if (part == 0) gold_pb[bI] = g;
    __syncthreads();                     // match chunk-0 barrier
    for (int c = 0; c < NCH; ++c) __syncthreads();
  }
}

__global__ void crf_mean(const float* __restrict__ fwd, const float* __restrict__ gold,
                         float* __restrict__ out) {
  const int tid = threadIdx.x;  // 64 threads, one wave
  float v = fwd[tid] - gold[tid];
  #pragma unroll
  for (int m = 1; m < 64; m <<= 1) v += __shfl_xor(v, m, 64);
  if (tid == 0) out[0] = v * (1.0f / 64.0f);
}

extern "C" void kernel_launch(void* const* d_in, const int* in_sizes, int n_in,
                              void* d_out, int out_size, void* d_ws, size_t ws_size,
                              hipStream_t stream) {
  const float* feats = (const float*)d_in[0];
  const int*   tags  = (const int*)d_in[1];
  const int*   lens  = (const int*)d_in[2];
  const float* trans = (const float*)d_in[3];
  float* fwd_pb  = (float*)d_ws;        // 64 floats
  float* gold_pb = fwd_pb + 64;         // 64 floats
  crf_forward_mfma<<<BB / NB, 256, 0, stream>>>(feats, tags, lens, trans, fwd_pb, gold_pb);
  crf_mean<<<1, 64, 0, stream>>>(fwd_pb, gold_pb, (float*)d_out);
}